// Round 5
// baseline (404.888 us; speedup 1.0000x reference)
//
#include <hip/hip_runtime.h>

// ---------------- problem constants ----------------
#define F_BINS 257
#define NCH    8
#define NSRC   2
#define KW     5
#define HCH    32
#define TLEN   2000
#define BATCH  4

// ---------------- tiling ----------------
#define TT      64
#define NTILES  32          // 32*64 = 2048 >= 2000

// LDS layout (bytes). x tile: 84 cols (halo 10/10), 16 ch (pad to 24 halves)
#define XSTRIDE 24
#define XCOLS   84
#define XOFF    0
#define XSZ     (XCOLS * XSTRIDE * 2)          // 4032 B
#define HWIN    80                             // h1/h2 window: [t0-8, t0+72)
#define H1OFF   XSZ
#define HSZ     (HWIN * 64 * 2)                // 10240 B
#define H2OFF   (H1OFF + HSZ)                  // 14272
#define SMEM_BYTES (H2OFF + HSZ)               // 24512 B -> 6 blocks/CU
#define H3OFF   H1OFF                          // h3 aliases h1 (dead after L2)
#define H3STRIDE 40                            // halves per col (32 used + pad)

// packed weight fragments: [f][frag*2+mw][lane] of half8 (16B each)
#define NFRAG   36
#define PW_HALF8_PER_F (NFRAG * 2 * 64)
#define PW_BYTES ((size_t)F_BINS * PW_HALF8_PER_F * 16)   // ~18.9 MB

typedef _Float16 half8  __attribute__((ext_vector_type(8)));
typedef _Float16 half2t __attribute__((ext_vector_type(2)));
typedef float    f32x4  __attribute__((ext_vector_type(4)));

#define MFMA16(a, b, c) __builtin_amdgcn_mfma_f32_16x16x32_f16(a, b, c, 0, 0, 0)

// frag ids: a1[hr][p] = hr*3+p (0..5); a2[w][hr][kk] = 6+w*4+hr*2+kk (6..25);
//           a3[w][kk] = 26+w*2+kk (26..35)
__device__ __forceinline__ half8 gather_frag(
    int f, int frag, int mw, int lane,
    const float* __restrict__ Wr1, const float* __restrict__ Wi1,
    const float* __restrict__ Wr2, const float* __restrict__ Wi2,
    const float* __restrict__ Wr3, const float* __restrict__ Wi3)
{
    const int g = lane >> 4, r16 = lane & 15;
    half8 v;
    if (frag < 6) {
        int hr = frag / 3, p = frag % 3;
        int tap = 2 * p + (g >> 1);
        #pragma unroll
        for (int j = 0; j < 8; ++j) {
            float val = 0.f;
            if (tap < KW) {
                long idx = (((long)f * HCH + hr * 16 + r16) * NCH + j) * KW + tap;
                if (mw == 0) val = (g & 1) ? -Wi1[idx] : Wr1[idx];
                else         val = (g & 1) ?  Wr1[idx] : Wi1[idx];
            }
            v[j] = (_Float16)val;
        }
    } else if (frag < 26) {
        int u = frag - 6;
        int w = u >> 2, hr = (u >> 1) & 1, kk = u & 1;
        #pragma unroll
        for (int j = 0; j < 8; ++j) {
            int c = g * 8 + j;
            long idx = (((long)f * HCH + hr * 16 + r16) * HCH + c) * KW + w;
            float val;
            if (mw == 0) val = kk ? -Wi2[idx] : Wr2[idx];
            else         val = kk ?  Wr2[idx] : Wi2[idx];
            v[j] = (_Float16)val;
        }
    } else {
        int u = frag - 26;
        int w = u >> 1, kk = u & 1;
        #pragma unroll
        for (int j = 0; j < 8; ++j) {
            int c = g * 8 + j;
            long idx = (((long)f * (NCH * NSRC) + r16) * HCH + c) * KW + w;
            float val;
            if (mw == 0) val = kk ? -Wi3[idx] : Wr3[idx];
            else         val = kk ?  Wr3[idx] : Wi3[idx];
            v[j] = (_Float16)val;
        }
    }
    return v;
}

__global__ __launch_bounds__(256) void repack_kernel(
    const float* __restrict__ Wr1, const float* __restrict__ Wi1,
    const float* __restrict__ Wr2, const float* __restrict__ Wi2,
    const float* __restrict__ Wr3, const float* __restrict__ Wi3,
    _Float16* __restrict__ pw)
{
    const int bid  = blockIdx.x;
    const int f    = bid >> 2;
    const int part = bid & 3;
    const int lane = threadIdx.x & 63;
    const int q    = threadIdx.x >> 6;
    half8* pwv = (half8*)pw;
    for (int u = part * 18 + q; u < part * 18 + 18; u += 4) {
        int frag = u >> 1, mw = u & 1;
        half8 v = gather_frag(f, frag, mw, lane, Wr1, Wi1, Wr2, Wi2, Wr3, Wi3);
        pwv[((size_t)f * (NFRAG * 2) + u) * 64 + lane] = v;
    }
}

template<bool PACKED>
__global__ __launch_bounds__(256, 6) void cddcnn_mfma_kernel(
    const float* __restrict__ x,
    const float* __restrict__ Wr1, const float* __restrict__ Wi1,
    const float* __restrict__ Wr2, const float* __restrict__ Wi2,
    const float* __restrict__ Wr3, const float* __restrict__ Wi3,
    float* __restrict__ out, const _Float16* __restrict__ pw)
{
    __shared__ __align__(16) char sm[SMEM_BYTES];

    const int tid  = threadIdx.x;
    const int lane = tid & 63;
    const int wv   = tid >> 6;      // wave id 0..3 -> owns col-block wv
    const int g    = lane >> 4;
    const int r16  = lane & 15;
    const int mw4  = wv >> 1;       // cb4 row-tile owned by this wave
    const int hr4  = wv & 1;

    const int bid = blockIdx.x;
    const int tl  = bid % NTILES;
    const int f   = (bid / NTILES) % F_BINS;
    const int b   = bid / (NTILES * F_BINS);
    const int t0  = tl * TT;
    const bool interior = (tl >= 1) && (tl <= 30);

    const int colb  = wv * 16 + r16;     // own col (cb = wv), 0..63
    const int col4  = 64 + r16;          // 5th col-block col
    const int cb4d  = 64 - wv * 16;      // col delta own -> cb4 (mult of 8)

    const half8* pwf = PACKED ? ((const half8*)pw) + (size_t)f * PW_HALF8_PER_F + lane
                              : nullptr;
    #define LOADFRAG(fr, mww) (PACKED ? pwf[((fr) * 2 + (mww)) * 64] \
                  : gather_frag(f, (fr), (mww), lane, Wr1, Wi1, Wr2, Wi2, Wr3, Wi3))

    const long xr_base = ((long)(b * 2 * F_BINS + f) * NCH) * TLEN;
    const long xi_base = ((long)(b * 2 * F_BINS + F_BINS + f) * NCH) * TLEN;

    // ---- Phase X: stage x tile as fp16 [84 cols][16 ch], halo 10 ----
    for (int e = tid; e < XCOLS * 16; e += 256) {
        int pc  = e / XCOLS;
        int idx = e - pc * XCOLS;
        int t   = t0 - 10 + idx;
        float val = 0.f;
        if (t >= 0 && t < TLEN) {
            long base = (pc < 8) ? (xr_base + (long)pc * TLEN)
                                 : (xi_base + (long)(pc - 8) * TLEN);
            val = x[base + t];
        }
        *(_Float16*)(sm + XOFF + (idx * XSTRIDE + pc) * 2) = (_Float16)val;
    }
    __syncthreads();

    const int Xc = (r16 & 7) << 4;       // swizzle XOR (col&7 == r16&7 for own & cb4)

    // epilogue helper (macro-free, static): writes one (mw,hr,q) half2
    #define EPI_WRITE(wbase, accv, mww, hrr, qq, okv)                        \
        {                                                                    \
            float v0 = (okv) ? fmaxf((accv)[2*(qq)],     0.f) : 0.f;         \
            float v1 = (okv) ? fmaxf((accv)[2*(qq) + 1], 0.f) : 0.f;         \
            half2t hv; hv[0] = (_Float16)v0; hv[1] = (_Float16)v1;           \
            *(half2t*)((wbase) + ((((mww)*64 + (hrr)*32 + g*8 + (qq)*4)) ^ Xc)) = hv; \
        }

    // ---- Phase L1: h1 = relu(cconv(x, W1)) over 80-col window ----
    {
        f32x4 acc00 = {}, acc01 = {}, acc10 = {}, acc11 = {}, acc4 = {};
        const char* xb = sm + XOFF + (colb * XSTRIDE + (g & 1) * 8) * 2;
        #pragma unroll
        for (int p = 0; p < 3; ++p) {
            int tap = 2 * p + (g >> 1);
            if (tap > 4) tap = 4;          // A is zero for these groups
            const half8 b0 = *(const half8*)(xb + tap * (XSTRIDE * 2));
            const half8 b4 = *(const half8*)(xb + tap * (XSTRIDE * 2) + cb4d * (XSTRIDE * 2));
            const half8 a00 = LOADFRAG(p,     0);
            const half8 a01 = LOADFRAG(3 + p, 0);
            const half8 a10 = LOADFRAG(p,     1);
            const half8 a11 = LOADFRAG(3 + p, 1);
            const half8 af4 = LOADFRAG(hr4 * 3 + p, mw4);
            acc00 = MFMA16(a00, b0, acc00);
            acc01 = MFMA16(a01, b0, acc01);
            acc10 = MFMA16(a10, b0, acc10);
            acc11 = MFMA16(a11, b0, acc11);
            acc4  = MFMA16(af4, b4, acc4);
        }
        char* wb  = sm + H1OFF + colb * 128;
        char* wb4 = sm + H1OFF + col4 * 128;
        bool ok  = interior || ((t0 - 8 + colb >= 0) && (t0 - 8 + colb < TLEN));
        bool ok4 = interior || ((t0 + 56 + r16 >= 0) && (t0 + 56 + r16 < TLEN));
        #pragma unroll
        for (int q = 0; q < 2; ++q) {
            EPI_WRITE(wb, acc00, 0, 0, q, ok);
            EPI_WRITE(wb, acc01, 0, 1, q, ok);
            EPI_WRITE(wb, acc10, 1, 0, q, ok);
            EPI_WRITE(wb, acc11, 1, 1, q, ok);
            EPI_WRITE(wb4, acc4, mw4, hr4, q, ok4);
        }
    }
    __syncthreads();

    // ---- Phase L2: h2 = relu(cconv(h1, W2)) over 80-col window ----
    {
        f32x4 acc00 = {}, acc01 = {}, acc10 = {}, acc11 = {}, acc4 = {};
        #pragma unroll
        for (int u = 0; u < KW; ++u)
        #pragma unroll
        for (int kk = 0; kk < 2; ++kk) {
            const half8 a00 = LOADFRAG(6 + u * 4 + 0 + kk, 0);
            const half8 a01 = LOADFRAG(6 + u * 4 + 2 + kk, 0);
            const half8 a10 = LOADFRAG(6 + u * 4 + 0 + kk, 1);
            const half8 a11 = LOADFRAG(6 + u * 4 + 2 + kk, 1);
            const half8 af4 = LOADFRAG(6 + u * 4 + hr4 * 2 + kk, mw4);
            const int sc0 = colb + u - 2;
            const char* rb = sm + H1OFF + sc0 * 128
                           + ((kk * 64 + g * 16) ^ ((sc0 & 7) << 4));
            const half8 b0 = *(const half8*)rb;
            const half8 b4 = *(const half8*)(rb + cb4d * 128);
            acc00 = MFMA16(a00, b0, acc00);
            acc01 = MFMA16(a01, b0, acc01);
            acc10 = MFMA16(a10, b0, acc10);
            acc11 = MFMA16(a11, b0, acc11);
            acc4  = MFMA16(af4, b4, acc4);
        }
        char* wb  = sm + H2OFF + colb * 128;
        char* wb4 = sm + H2OFF + col4 * 128;
        bool ok  = interior || ((t0 - 8 + colb >= 0) && (t0 - 8 + colb < TLEN));
        bool ok4 = interior || ((t0 + 56 + r16 >= 0) && (t0 + 56 + r16 < TLEN));
        #pragma unroll
        for (int q = 0; q < 2; ++q) {
            EPI_WRITE(wb, acc00, 0, 0, q, ok);
            EPI_WRITE(wb, acc01, 0, 1, q, ok);
            EPI_WRITE(wb, acc10, 1, 0, q, ok);
            EPI_WRITE(wb, acc11, 1, 1, q, ok);
            EPI_WRITE(wb4, acc4, mw4, hr4, q, ok4);
        }
    }
    __syncthreads();

    // ---- Phase L3: h3 = cconv(h2, W3) (no relu), 64 cols, own cb only ----
    {
        f32x4 acc30 = {}, acc31 = {};
        #pragma unroll
        for (int u = 0; u < KW; ++u)
        #pragma unroll
        for (int kk = 0; kk < 2; ++kk) {
            const half8 a30 = LOADFRAG(26 + u * 2 + kk, 0);
            const half8 a31 = LOADFRAG(26 + u * 2 + kk, 1);
            const int sc0 = colb + 6 + u;
            const char* rb = sm + H2OFF + sc0 * 128
                           + ((kk * 64 + g * 16) ^ ((sc0 & 7) << 4));
            const half8 bf = *(const half8*)rb;
            acc30 = MFMA16(a30, bf, acc30);
            acc31 = MFMA16(a31, bf, acc31);
        }
        char* wb3 = sm + H3OFF + colb * (H3STRIDE * 2) + g * 8;
        #pragma unroll
        for (int q = 0; q < 2; ++q) {
            half2t hv0, hv1;
            hv0[0] = (_Float16)acc30[2 * q]; hv0[1] = (_Float16)acc30[2 * q + 1];
            hv1[0] = (_Float16)acc31[2 * q]; hv1[1] = (_Float16)acc31[2 * q + 1];
            *(half2t*)(wb3 + 0  + q * 4) = hv0;   // och = g*4+2q      (real)
            *(half2t*)(wb3 + 32 + q * 4) = hv1;   // och = 16+g*4+2q   (imag)
        }
    }
    __syncthreads();

    // ---- Phase M: mask multiply + channel reduce + store ----
    if (tid < 2 * TT) {
        int s   = tid >> 6;         // 0..1
        int col = tid & 63;
        int t = t0 + col;
        if (t < TLEN) {
            const half8 xrv = *(const half8*)(sm + XOFF + ((col + 10) * XSTRIDE + 0) * 2);
            const half8 xiv = *(const half8*)(sm + XOFF + ((col + 10) * XSTRIDE + 8) * 2);
            half8 h3q[4];
            #pragma unroll
            for (int q = 0; q < 4; ++q)
                h3q[q] = *(const half8*)(sm + H3OFF + col * (H3STRIDE * 2) + q * 16);
            float Yr = 0.f, Yi = 0.f;
            #pragma unroll
            for (int c = 0; c < NCH; ++c) {
                float vr = (float)xrv[c];
                float vi = (float)xiv[c];
                int o = 2 * c + s;
                float hr = (c < 4) ? (float)h3q[0][o] : (float)h3q[1][o - 8];
                float hi = (c < 4) ? (float)h3q[2][o] : (float)h3q[3][o - 8];
                Yr += vr * hr - vi * hi;
                Yi += vr * hi + vi * hr;
            }
            out[((long)(b * 2 * F_BINS + f) * NSRC + s) * TLEN + t]          = Yr;
            out[((long)(b * 2 * F_BINS + F_BINS + f) * NSRC + s) * TLEN + t] = Yi;
        }
    }
}

extern "C" void kernel_launch(void* const* d_in, const int* in_sizes, int n_in,
                              void* d_out, int out_size, void* d_ws, size_t ws_size,
                              hipStream_t stream) {
    const float* x   = (const float*)d_in[0];
    const float* Wr1 = (const float*)d_in[1];
    const float* Wi1 = (const float*)d_in[2];
    const float* Wr2 = (const float*)d_in[3];
    const float* Wi2 = (const float*)d_in[4];
    const float* Wr3 = (const float*)d_in[5];
    const float* Wi3 = (const float*)d_in[6];
    float* out = (float*)d_out;

    dim3 block(256);
    dim3 grid(BATCH * F_BINS * NTILES);
    if (ws_size >= PW_BYTES) {
        _Float16* pw = (_Float16*)d_ws;
        repack_kernel<<<F_BINS * 4, block, 0, stream>>>(Wr1, Wi1, Wr2, Wi2, Wr3, Wi3, pw);
        cddcnn_mfma_kernel<true><<<grid, block, 0, stream>>>(
            x, Wr1, Wi1, Wr2, Wi2, Wr3, Wi3, out, pw);
    } else {
        cddcnn_mfma_kernel<false><<<grid, block, 0, stream>>>(
            x, Wr1, Wi1, Wr2, Wi2, Wr3, Wi3, out, nullptr);
    }
}

// Round 7
// 256.449 us; speedup vs baseline: 1.5788x; 1.5788x over previous
//
#include <hip/hip_runtime.h>

// ---------------- problem constants ----------------
#define F_BINS 257
#define NCH    8
#define NSRC   2
#define KW     5
#define HCH    32
#define TLEN   2000
#define BATCH  4

// ---------------- tiling ----------------
#define TT      128
#define NTILES  16          // 16*128 = 2048 >= 2000

// LDS layout (bytes). x tile: 148 cols (halo 10/10), 16 ch (pad to 24 halves)
#define XSTRIDE 24
#define XCOLS   148
#define XOFF    0
#define XSZ     (XCOLS * XSTRIDE * 2)          // 7104 B
#define HWIN    144                            // h1/h2 window: [t0-8, t0+136)
#define H1OFF   XSZ
#define HSZ     (HWIN * 64 * 2)                // 18432 B
#define H2OFF   (H1OFF + HSZ)
#define SMEM_BYTES (H2OFF + HSZ)               // 43968 B -> 3 blocks/CU
#define H3OFF   H1OFF                          // h3 aliases h1 (dead after L2)
#define H3STRIDE 40                            // halves per col (32 used + pad)

// packed weight fragments: [f][frag*2+mw][lane] of half8 (16B each)
#define NFRAG   36
#define PW_HALF8_PER_F (NFRAG * 2 * 64)
#define PW_BYTES ((size_t)F_BINS * PW_HALF8_PER_F * 16)   // ~18.9 MB

typedef _Float16 half8  __attribute__((ext_vector_type(8)));
typedef __fp16   pk16x2 __attribute__((ext_vector_type(2)));   // cvt_pkrtz result type
typedef float    f32x4  __attribute__((ext_vector_type(4)));

#define MFMA16(a, b, c) __builtin_amdgcn_mfma_f32_16x16x32_f16(a, b, c, 0, 0, 0)

// frag ids: a1[hr][p] = hr*3+p (0..5); a2[w][hr][kk] = 6+w*4+hr*2+kk (6..25);
//           a3[w][kk] = 26+w*2+kk (26..35)
__device__ __forceinline__ half8 gather_frag(
    int f, int frag, int mw, int lane,
    const float* __restrict__ Wr1, const float* __restrict__ Wi1,
    const float* __restrict__ Wr2, const float* __restrict__ Wi2,
    const float* __restrict__ Wr3, const float* __restrict__ Wi3)
{
    const int g = lane >> 4, r16 = lane & 15;
    half8 v;
    if (frag < 6) {
        int hr = frag / 3, p = frag % 3;
        int tap = 2 * p + (g >> 1);
        #pragma unroll
        for (int j = 0; j < 8; ++j) {
            float val = 0.f;
            if (tap < KW) {
                long idx = (((long)f * HCH + hr * 16 + r16) * NCH + j) * KW + tap;
                if (mw == 0) val = (g & 1) ? -Wi1[idx] : Wr1[idx];
                else         val = (g & 1) ?  Wr1[idx] : Wi1[idx];
            }
            v[j] = (_Float16)val;
        }
    } else if (frag < 26) {
        int u = frag - 6;
        int w = u >> 2, hr = (u >> 1) & 1, kk = u & 1;
        #pragma unroll
        for (int j = 0; j < 8; ++j) {
            int c = g * 8 + j;
            long idx = (((long)f * HCH + hr * 16 + r16) * HCH + c) * KW + w;
            float val;
            if (mw == 0) val = kk ? -Wi2[idx] : Wr2[idx];
            else         val = kk ?  Wr2[idx] : Wi2[idx];
            v[j] = (_Float16)val;
        }
    } else {
        int u = frag - 26;
        int w = u >> 1, kk = u & 1;
        #pragma unroll
        for (int j = 0; j < 8; ++j) {
            int c = g * 8 + j;
            long idx = (((long)f * (NCH * NSRC) + r16) * HCH + c) * KW + w;
            float val;
            if (mw == 0) val = kk ? -Wi3[idx] : Wr3[idx];
            else         val = kk ?  Wr3[idx] : Wi3[idx];
            v[j] = (_Float16)val;
        }
    }
    return v;
}

__global__ __launch_bounds__(256) void repack_kernel(
    const float* __restrict__ Wr1, const float* __restrict__ Wi1,
    const float* __restrict__ Wr2, const float* __restrict__ Wi2,
    const float* __restrict__ Wr3, const float* __restrict__ Wi3,
    _Float16* __restrict__ pw)
{
    const int bid  = blockIdx.x;
    const int f    = bid >> 2;
    const int part = bid & 3;
    const int lane = threadIdx.x & 63;
    const int q    = threadIdx.x >> 6;
    half8* pwv = (half8*)pw;
    for (int u = part * 18 + q; u < part * 18 + 18; u += 4) {
        int frag = u >> 1, mw = u & 1;
        half8 v = gather_frag(f, frag, mw, lane, Wr1, Wi1, Wr2, Wi2, Wr3, Wi3);
        pwv[((size_t)f * (NFRAG * 2) + u) * 64 + lane] = v;
    }
}

template<bool PACKED>
__global__ __launch_bounds__(256, 3) void cddcnn_mfma_kernel(
    const float* __restrict__ x,
    const float* __restrict__ Wr1, const float* __restrict__ Wi1,
    const float* __restrict__ Wr2, const float* __restrict__ Wi2,
    const float* __restrict__ Wr3, const float* __restrict__ Wi3,
    float* __restrict__ out, const _Float16* __restrict__ pw)
{
    __shared__ __align__(16) char sm[SMEM_BYTES];

    const int tid  = threadIdx.x;
    const int lane = tid & 63;
    const int wv   = tid >> 6;
    const int mw   = wv >> 1;       // 0: real-out rows, 1: imag-out rows
    const int nw   = wv & 1;        // n-half
    const int g    = lane >> 4;
    const int r16  = lane & 15;

    const int bid = blockIdx.x;
    const int tl  = bid % NTILES;
    const int f   = (bid / NTILES) % F_BINS;
    const int b   = bid / (NTILES * F_BINS);
    const int t0  = tl * TT;

    const int nb0 = nw ? 5 : 0;
    const int nbn = nw ? 4 : 5;

    const half8* pwf = PACKED ? ((const half8*)pw) + (size_t)f * PW_HALF8_PER_F + mw * 64 + lane
                              : nullptr;
    #define LOADFRAG(fr) (PACKED ? pwf[(fr) * 128] \
                                 : gather_frag(f, (fr), mw, lane, Wr1, Wi1, Wr2, Wi2, Wr3, Wi3))

    const long xr_base = ((long)(b * 2 * F_BINS + f) * NCH) * TLEN;
    const long xi_base = ((long)(b * 2 * F_BINS + F_BINS + f) * NCH) * TLEN;

    // ---- prefetch L1 weight frags (latency hidden under phase X) ----
    half8 a1[2][3];
    #pragma unroll
    for (int hr = 0; hr < 2; ++hr)
    #pragma unroll
    for (int p = 0; p < 3; ++p)
        a1[hr][p] = LOADFRAG(hr * 3 + p);

    // ---- Phase X: stage x tile as fp16 [148 cols][16 ch], halo 10 ----
    // units: 37 col-quads x 16 pc; two float2 loads per unit (8B aligned).
    for (int u = tid; u < 16 * 37; u += 256) {
        int pc  = u / 37;
        int q   = u - pc * 37;
        int idx = q * 4;
        int tt  = t0 - 10 + idx;
        long base = (pc < 8) ? (xr_base + (long)pc * TLEN)
                             : (xi_base + (long)(pc - 8) * TLEN);
        char* wp = sm + XOFF + (idx * XSTRIDE + pc) * 2;
        #pragma unroll
        for (int h = 0; h < 2; ++h) {
            int t2 = tt + 2 * h;
            float v0 = 0.f, v1 = 0.f;
            if (t2 >= 0 && t2 + 1 < TLEN) {          // t2 even: never straddles
                float2 xx = *(const float2*)(x + base + t2);
                v0 = xx.x; v1 = xx.y;
            } else {
                if (t2 >= 0 && t2 < TLEN)         v0 = x[base + t2];
                if (t2 + 1 >= 0 && t2 + 1 < TLEN) v1 = x[base + t2 + 1];
            }
            pk16x2 hv = __builtin_amdgcn_cvt_pkrtz(v0, v1);
            *(__fp16*)(wp + (2 * h)     * (XSTRIDE * 2)) = hv[0];
            *(__fp16*)(wp + (2 * h + 1) * (XSTRIDE * 2)) = hv[1];
        }
    }
    __syncthreads();

    const int Xc = (r16 & 7) << 4;       // swizzle XOR ((col&7) == (r16&7))
    int woff[2][2];                      // epi byte offsets: (mw*64+hr*32+g*8+q*4)^Xc
    #pragma unroll
    for (int hr = 0; hr < 2; ++hr)
    #pragma unroll
    for (int q = 0; q < 2; ++q)
        woff[hr][q] = ((mw * 64 + hr * 32 + g * 8 + q * 4) ^ Xc);

    half8 a2[5][2][2];   // [w][hr][kk]

    // ---- Phase L1: h1 = relu(cconv(x, W1)) over 144-col window ----
    {
        f32x4 acc[2][5] = {};

        // prefetch a2 first batch (w=0,1) — consumed next phase
        #pragma unroll
        for (int w = 0; w < 2; ++w)
        #pragma unroll
        for (int hr = 0; hr < 2; ++hr)
        #pragma unroll
        for (int kk = 0; kk < 2; ++kk)
            a2[w][hr][kk] = LOADFRAG(6 + w * 4 + hr * 2 + kk);

        const char* xb = sm + XOFF + ((nb0 * 16 + r16) * XSTRIDE + (g & 1) * 8) * 2;
        #pragma unroll
        for (int p = 0; p < 3; ++p) {
            int tap = 2 * p + (g >> 1);
            if (tap > 4) tap = 4;          // A is zero for these groups
            const char* xbp = xb + tap * (XSTRIDE * 2);
            #pragma unroll
            for (int nbi = 0; nbi < 5; ++nbi) {
                if (nbi < nbn) {
                    const half8 bf = *(const half8*)(xbp + nbi * (16 * XSTRIDE * 2));
                    acc[0][nbi] = MFMA16(a1[0][p], bf, acc[0][nbi]);
                    acc[1][nbi] = MFMA16(a1[1][p], bf, acc[1][nbi]);
                }
            }
        }

        // prefetch a2 second batch (w=2..4)
        #pragma unroll
        for (int w = 2; w < 5; ++w)
        #pragma unroll
        for (int hr = 0; hr < 2; ++hr)
        #pragma unroll
        for (int kk = 0; kk < 2; ++kk)
            a2[w][hr][kk] = LOADFRAG(6 + w * 4 + hr * 2 + kk);

        // epilogue
        char* wb = sm + H1OFF + (nb0 * 16 + r16) * 128;
        #pragma unroll
        for (int nbi = 0; nbi < 5; ++nbi) {
            if (nbi < nbn) {
                int t = t0 - 8 + nb0 * 16 + r16 + nbi * 16;
                bool ok = (t >= 0) && (t < TLEN);
                #pragma unroll
                for (int hr = 0; hr < 2; ++hr)
                #pragma unroll
                for (int q = 0; q < 2; ++q) {
                    float v0 = ok ? fmaxf(acc[hr][nbi][2 * q],     0.f) : 0.f;
                    float v1 = ok ? fmaxf(acc[hr][nbi][2 * q + 1], 0.f) : 0.f;
                    pk16x2 hv = __builtin_amdgcn_cvt_pkrtz(v0, v1);
                    *(pk16x2*)(wb + nbi * 2048 + woff[hr][q]) = hv;
                }
            }
        }
    }
    __syncthreads();

    half8 a3[5][2];      // [w][kk]

    // ---- Phase L2: h2 = relu(cconv(h1, W2)) over 144-col window ----
    {
        f32x4 acc[2][5] = {};
        #pragma unroll
        for (int w = 0; w < KW; ++w) {
            const int sc0 = nb0 * 16 + r16 + w - 2;
            const int vb  = sc0 * 128 + ((g * 16) ^ ((sc0 & 7) << 4));
            #pragma unroll
            for (int kk = 0; kk < 2; ++kk) {
                const char* rb = sm + H1OFF + (kk ? (vb ^ 64) : vb);
                #pragma unroll
                for (int nbi = 0; nbi < 5; ++nbi) {
                    if (nbi < nbn) {
                        const half8 bf = *(const half8*)(rb + nbi * 2048);
                        acc[0][nbi] = MFMA16(a2[w][0][kk], bf, acc[0][nbi]);
                        acc[1][nbi] = MFMA16(a2[w][1][kk], bf, acc[1][nbi]);
                    }
                }
            }
        }

        // prefetch a3 (consumed next phase)
        #pragma unroll
        for (int w = 0; w < KW; ++w)
        #pragma unroll
        for (int kk = 0; kk < 2; ++kk)
            a3[w][kk] = LOADFRAG(26 + w * 2 + kk);

        char* wb = sm + H2OFF + (nb0 * 16 + r16) * 128;
        #pragma unroll
        for (int nbi = 0; nbi < 5; ++nbi) {
            if (nbi < nbn) {
                int t = t0 - 8 + nb0 * 16 + r16 + nbi * 16;
                bool ok = (t >= 0) && (t < TLEN);
                #pragma unroll
                for (int hr = 0; hr < 2; ++hr)
                #pragma unroll
                for (int q = 0; q < 2; ++q) {
                    float v0 = ok ? fmaxf(acc[hr][nbi][2 * q],     0.f) : 0.f;
                    float v1 = ok ? fmaxf(acc[hr][nbi][2 * q + 1], 0.f) : 0.f;
                    pk16x2 hv = __builtin_amdgcn_cvt_pkrtz(v0, v1);
                    *(pk16x2*)(wb + nbi * 2048 + woff[hr][q]) = hv;
                }
            }
        }
    }
    __syncthreads();

    // ---- Phase L3: h3 = cconv(h2, W3) (no relu), 128 cols ----
    {
        f32x4 acc3[4] = {};
        #pragma unroll
        for (int w = 0; w < KW; ++w) {
            const int sc0 = nw * 64 + r16 + 6 + w;
            const int vb  = sc0 * 128 + ((g * 16) ^ ((sc0 & 7) << 4));
            #pragma unroll
            for (int kk = 0; kk < 2; ++kk) {
                const char* rb = sm + H2OFF + (kk ? (vb ^ 64) : vb);
                #pragma unroll
                for (int nbi = 0; nbi < 4; ++nbi) {
                    const half8 bf = *(const half8*)(rb + nbi * 2048);
                    acc3[nbi] = MFMA16(a3[w][kk], bf, acc3[nbi]);
                }
            }
        }
        char* wb3 = sm + H3OFF + (nw * 64 + r16) * (H3STRIDE * 2) + mw * 32 + g * 8;
        #pragma unroll
        for (int nbi = 0; nbi < 4; ++nbi)
        #pragma unroll
        for (int q = 0; q < 2; ++q) {
            pk16x2 hv = __builtin_amdgcn_cvt_pkrtz(acc3[nbi][2 * q], acc3[nbi][2 * q + 1]);
            *(pk16x2*)(wb3 + nbi * (16 * H3STRIDE * 2) + q * 4) = hv;
        }
    }
    __syncthreads();

    // ---- Phase M: mask multiply + channel reduce + store (all 256 threads) ----
    {
        int s   = tid >> 7;         // 0..1
        int col = tid & 127;
        int t = t0 + col;
        if (t < TLEN) {
            const half8 xrv = *(const half8*)(sm + XOFF + ((col + 10) * XSTRIDE + 0) * 2);
            const half8 xiv = *(const half8*)(sm + XOFF + ((col + 10) * XSTRIDE + 8) * 2);
            half8 h3q[4];
            #pragma unroll
            for (int q = 0; q < 4; ++q)
                h3q[q] = *(const half8*)(sm + H3OFF + col * (H3STRIDE * 2) + q * 16);
            float Yr = 0.f, Yi = 0.f;
            #pragma unroll
            for (int c = 0; c < NCH; ++c) {
                float vr = (float)xrv[c];
                float vi = (float)xiv[c];
                int o = 2 * c + s;
                float hr = (c < 4) ? (float)h3q[0][o] : (float)h3q[1][o - 8];
                float hi = (c < 4) ? (float)h3q[2][o] : (float)h3q[3][o - 8];
                Yr += vr * hr - vi * hi;
                Yi += vr * hi + vi * hr;
            }
            out[((long)(b * 2 * F_BINS + f) * NSRC + s) * TLEN + t]          = Yr;
            out[((long)(b * 2 * F_BINS + F_BINS + f) * NSRC + s) * TLEN + t] = Yi;
        }
    }
}

extern "C" void kernel_launch(void* const* d_in, const int* in_sizes, int n_in,
                              void* d_out, int out_size, void* d_ws, size_t ws_size,
                              hipStream_t stream) {
    const float* x   = (const float*)d_in[0];
    const float* Wr1 = (const float*)d_in[1];
    const float* Wi1 = (const float*)d_in[2];
    const float* Wr2 = (const float*)d_in[3];
    const float* Wi2 = (const float*)d_in[4];
    const float* Wr3 = (const float*)d_in[5];
    const float* Wi3 = (const float*)d_in[6];
    float* out = (float*)d_out;

    dim3 block(256);
    dim3 grid(BATCH * F_BINS * NTILES);
    if (ws_size >= PW_BYTES) {
        _Float16* pw = (_Float16*)d_ws;
        repack_kernel<<<F_BINS * 4, block, 0, stream>>>(Wr1, Wi1, Wr2, Wi2, Wr3, Wi3, pw);
        cddcnn_mfma_kernel<true><<<grid, block, 0, stream>>>(
            x, Wr1, Wi1, Wr2, Wi2, Wr3, Wi3, out, pw);
    } else {
        cddcnn_mfma_kernel<false><<<grid, block, 0, stream>>>(
            x, Wr1, Wi1, Wr2, Wi2, Wr3, Wi3, out, nullptr);
    }
}